// Round 13
// baseline (3057.760 us; speedup 1.0000x reference)
//
#include <hip/hip_runtime.h>
#include <hip/hip_bf16.h>
#include <cstdint>
#include <cstddef>

#define DI __device__ __forceinline__
#define RLX __ATOMIC_RELAXED
#define AGT __HIP_MEMORY_SCOPE_AGENT
#define WGP __HIP_MEMORY_SCOPE_WORKGROUP

typedef __attribute__((ext_vector_type(8))) short          bf16x8;
typedef __attribute__((ext_vector_type(8))) unsigned short u16x8;
typedef __attribute__((ext_vector_type(4))) unsigned short u16x4;
typedef __attribute__((ext_vector_type(4))) float          f32x4;

// ---- problem constants ----
constexpr int Sv = 512, Bv = 128, Dv = 512, Hv = 256;
constexpr int LMAX = 5;   // run-length cap (LDS-bounded)

// ---- workspace layout (bytes) ----
constexpr size_t SZ_FCSUM  = (size_t)128 * 513 * 256 * 4;            // 67,239,936 (zeroed AFTER gemm)
constexpr size_t OFF_FCSUM = 0;
constexpr size_t OFF_HX    = SZ_FCSUM;                               // poisoned 0xFF AFTER gemm
constexpr size_t SZ_HX     = (size_t)511 * 128 * 256 * 4;            // 66,977,792
constexpr size_t OFF_GSUM  = OFF_HX + SZ_HX;                         // 134,217,728
constexpr size_t SZ_GSUM   = (size_t)128 * 513 * 768 * 4;            // 201,719,808
constexpr size_t OFF_XF    = OFF_GSUM + SZ_GSUM;
constexpr size_t SZ_XF     = (size_t)512 * 128 * 256 * 4;            // 67,108,864
constexpr size_t OFF_BTH   = OFF_XF + SZ_XF;
constexpr size_t OFF_BTL   = OFF_BTH + (size_t)1024 * 512 * 2;
constexpr size_t OFF_UH    = OFF_BTL + (size_t)1024 * 512 * 2;
constexpr size_t OFF_UL    = OFF_UH + (size_t)1024 * 256 * 2;
constexpr size_t OFF_RUNS  = OFF_UL + (size_t)1024 * 256 * 2;        // 8 * 513 ints
constexpr size_t OFF_NRUN  = OFF_RUNS + (size_t)8 * 513 * 4;         // 8 ints
// A pre-split buffers ALIAS the fcsum+hx region (exactly 128 MiB combined).
constexpr size_t OFF_ATH   = 0;
constexpr size_t SZ_ATH    = (size_t)65536 * 512 * 2;                // 67,108,864
constexpr size_t OFF_ATL   = OFF_ATH + SZ_ATH;

// ---- scan LDS layout (bytes) ----
constexpr int LDS_AH   = 0;
constexpr int LDS_AL   = LDS_AH + LMAX * 8192;
constexpr int LDS_GCOR = LDS_AL + LMAX * 8192;          // [LMAX][16][96] f32
constexpr int LDS_FCOR = LDS_GCOR + LMAX * 6144;        // [LMAX][16][32] f32
constexpr int LDS_CBUF = LDS_FCOR + LMAX * 2048;        // [LMAX][16][32] f32
constexpr int LDS_RTAB = LDS_CBUF + LMAX * 2048;        // [513] u16
constexpr int LDS_SCAN = LDS_RTAB + 1040;               // = 134,160 -> 134,400

DI unsigned short f2bf(float x) {  // RNE float->bf16 bits
  union { float f; uint32_t u; } v; v.f = x;
  uint32_t r = v.u + 0x7fffu + ((v.u >> 16) & 1u);
  return (unsigned short)(r >> 16);
}
DI float bf2f(unsigned short b) {
  union { uint32_t u; float f; } v; v.u = ((uint32_t)b) << 16; return v.f;
}
DI float sigm(float x) { return 1.0f / (1.0f + __expf(-x)); }
DI float tanh_fast(float x) {
  float xc = fminf(fmaxf(x, -9.0f), 9.0f);
  float e = __expf(2.0f * xc);
  return (e - 1.0f) / (e + 1.0f);
}
// validity: packed h dword has hh exponent bits[30:23] != 0xFF (|h|<=1 -> exp<=0x7F).
DI bool okd(unsigned d) { return (d & 0x7F800000u) != 0x7F800000u; }
DI bool ok64(unsigned long long v) { return okd((unsigned)v) && okd((unsigned)(v >> 32)); }

// =============== W transpose + bf16 hi/lo split ===============
__global__ void cvt_w_kernel(const float* __restrict__ Wiou, const float* __restrict__ Wf,
                             unsigned short* __restrict__ bth, unsigned short* __restrict__ btl)
{
  int idx = blockIdx.x * 256 + threadIdx.x;
  int n = idx >> 9, k = idx & 511;
  float v = (n < 768) ? Wiou[(size_t)k * 768 + n] : Wf[(size_t)k * 256 + (n - 768)];
  unsigned short h = f2bf(v);
  bth[idx] = h;
  btl[idx] = f2bf(v - bf2f(h));
}

// =============== U -> bf16 hi/lo, [col][k] ===============
__global__ void cvt_u_kernel(const float* __restrict__ Uiou, const float* __restrict__ Uf,
                             unsigned short* __restrict__ uh, unsigned short* __restrict__ ul)
{
  int idx = blockIdx.x * 256 + threadIdx.x;
  int col = idx >> 8, k = idx & 255;
  float v = (col < 768) ? Uiou[(size_t)k * 768 + col] : Uf[(size_t)k * 256 + (col - 768)];
  unsigned short h = f2bf(v);
  uh[idx] = h;
  ul[idx] = f2bf(v - bf2f(h));
}

// =============== A -> bf16 hi/lo ===============
__global__ void cvt_a_kernel(const float* __restrict__ A,
                             unsigned short* __restrict__ ath, unsigned short* __restrict__ atl)
{
  int idx = blockIdx.x * 256 + threadIdx.x;
  f32x4 v = ((const f32x4*)A)[idx];
  u16x4 h, l;
  #pragma unroll
  for (int q = 0; q < 4; ++q) {
    h[q] = f2bf(v[q]);
    l[q] = f2bf(v[q] - bf2f(h[q]));
  }
  ((u16x4*)ath)[idx] = h;
  ((u16x4*)atl)[idx] = l;
}

// =============== run tables (cap LMAX): no intra-run parent edges ===============
__global__ void run_kernel(const int* __restrict__ parents, int* __restrict__ runsg,
                           int* __restrict__ nrung)
{
  __shared__ int pmin[512];
  __shared__ unsigned short rt[513];
  __shared__ int nr_sh;
  const int g = blockIdx.x, tid = threadIdx.x;
  int mn = 1 << 30;
  #pragma unroll
  for (int b = 0; b < 16; ++b) mn = min(mn, parents[(g * 16 + b) * 512 + tid]);
  pmin[tid] = mn;
  __syncthreads();
  if (tid == 0) {
    int r = 0, a = 0;
    while (a < 512) {
      rt[r++] = (unsigned short)a;
      int b = a + 1, m = pmin[a];
      while (b < 512 && (b - a) < LMAX) {
        int m2 = min(m, pmin[b]);
        if (m2 >= b + 1) { m = m2; ++b; } else break;
      }
      a = b;
    }
    rt[r] = 512;
    nr_sh = r;
    nrung[g] = r;
  }
  __syncthreads();
  for (int i = tid; i <= nr_sh; i += 512) runsg[g * 513 + i] = rt[i];
}

// =============== split-bf16 GEMM (R12, verified) ===============
#define GLD_LDS16(gp, lp) __builtin_amdgcn_global_load_lds( \
    (const __attribute__((address_space(1))) unsigned int*)(gp), \
    (__attribute__((address_space(3))) unsigned int*)(lp), 16, 0, 0)

__global__ __launch_bounds__(256, 2)
void gemm_split_kernel(const unsigned short* __restrict__ ATh,
                       const unsigned short* __restrict__ ATl,
                       const unsigned short* __restrict__ BTh,
                       const unsigned short* __restrict__ BTl,
                       const float* __restrict__ biou, const float* __restrict__ bfv,
                       float* __restrict__ gsum, float* __restrict__ xf)
{
  extern __shared__ char lds[];
  unsigned short* As = (unsigned short*)lds;
  unsigned short* Bs = (unsigned short*)(lds + 32768);

  const int bid = blockIdx.x;
  const int ntile = bid & 7, mtile = bid >> 3;
  const int m0 = mtile * 128, n0 = ntile * 128;
  const int tid = threadIdx.x;
  const int lane = tid & 63, w = tid >> 6;
  const int wr = w >> 1, wc = w & 1;

  f32x4 acc[4][4];
  #pragma unroll
  for (int i = 0; i < 4; i++)
    #pragma unroll
    for (int jj = 0; jj < 4; jj++) acc[i][jj] = f32x4{0.f, 0.f, 0.f, 0.f};

  auto stage = [&](unsigned short* dstbase, const unsigned short* src0,
                   int row0, int kk0, int buf) {
    #pragma unroll
    for (int q = 0; q < 4; ++q) {
      int cidx = q * 256 + tid;
      int row = cidx >> 3, blk = cidx & 7;
      const unsigned short* gp = src0 + (size_t)(row0 + row) * 512 + kk0 + blk * 8;
      unsigned short* lp = dstbase + buf * 8192 + cidx * 8;
      GLD_LDS16(gp, lp);
    }
  };

  stage(As, ATh, m0, 0, 0);
  stage(Bs, BTh, n0, 0, 0);
  asm volatile("s_waitcnt vmcnt(0)" ::: "memory");
  __syncthreads();

  for (int t = 0; t < 24; ++t) {
    const int buf = t & 1;
    if (t < 23) {
      const int tn = t + 1;
      stage(As, (tn >= 8 && tn < 16) ? ATl : ATh, m0, (tn & 7) * 64, buf ^ 1);
      stage(Bs, (tn < 16) ? BTh : BTl, n0, (tn & 7) * 64, buf ^ 1);
    }
    #pragma unroll
    for (int kk = 0; kk < 64; kk += 32) {
      const int k8 = (lane >> 4) * 8;
      bf16x8 af[4], bfrag[4];
      #pragma unroll
      for (int mi = 0; mi < 4; ++mi)
        af[mi] = *(const bf16x8*)(As + buf * 8192 + (size_t)(wr * 64 + mi * 16 + (lane & 15)) * 64 + kk + k8);
      #pragma unroll
      for (int ni = 0; ni < 4; ++ni)
        bfrag[ni] = *(const bf16x8*)(Bs + buf * 8192 + (size_t)(wc * 64 + ni * 16 + (lane & 15)) * 64 + kk + k8);
      #pragma unroll
      for (int mi = 0; mi < 4; ++mi)
        #pragma unroll
        for (int ni = 0; ni < 4; ++ni)
          acc[mi][ni] = __builtin_amdgcn_mfma_f32_16x16x32_bf16(af[mi], bfrag[ni], acc[mi][ni], 0, 0, 0);
    }
    asm volatile("s_waitcnt vmcnt(0)" ::: "memory");
    __syncthreads();
  }

  const bool isiou = (n0 < 768);
  const int s_ = mtile;
  #pragma unroll
  for (int ni = 0; ni < 4; ++ni) {
    int coln = n0 + wc * 64 + ni * 16 + (lane & 15);
    float bv = isiou ? biou[coln] : bfv[coln - 768];
    #pragma unroll
    for (int mi = 0; mi < 4; ++mi)
      #pragma unroll
      for (int r = 0; r < 4; ++r) {
        int bg = wr * 64 + mi * 16 + (lane >> 4) * 4 + r;
        float v = acc[mi][ni][r] + bv;
        if (isiou) gsum[((size_t)bg * 513 + s_) * 768 + coln] = v;
        else       xf[((size_t)s_ * 128 + bg) * 256 + (coln - 768)] = v;
      }
  }
}

// =============== scan by RUNS v2 (R7 pipelining discipline) ===============
// Per iteration (run r): ONE combined data-poll for all Lp prev-run blocks ->
// stage barrier (orders every thread's poll-vmcnt(0) drain) -> post-barrier
// prefetch of current-run gsum/fcsum rows + parent tags (overlaps phase B) ->
// phase B MFMA per prev-run child (near parents p<b -> child-indexed LDS corr;
// far -> WGP atomic, drained by next poll) -> barrier -> batched activation
// with tag-gathered corrections -> batched publish -> epilogue xf prefetch.
__global__ __launch_bounds__(512, 1)
void scan_kernel(const unsigned short* __restrict__ ubh, const unsigned short* __restrict__ ubl,
                 const float* __restrict__ xf, const int* __restrict__ parents,
                 float* gsum, float* fcsum, unsigned* hx,
                 const int* __restrict__ runsg, const int* __restrict__ nrung,
                 float* __restrict__ out)
{
  extern __shared__ char lds[];
  unsigned short* AH   = (unsigned short*)(lds + LDS_AH);    // [LMAX][4096]
  unsigned short* AL   = (unsigned short*)(lds + LDS_AL);    // [LMAX][4096]
  float*          gcor = (float*)(lds + LDS_GCOR);           // [LMAX][16][96] child-indexed
  float*          fcor = (float*)(lds + LDS_FCOR);           // [LMAX][16][32]
  float*          cbuf = (float*)(lds + LDS_CBUF);           // [LMAX][16][32]
  unsigned short* rtab = (unsigned short*)(lds + LDS_RTAB);  // [513]

  const int bid = blockIdx.x;
  const int g = bid & 7, j = bid >> 3;
  const int tid = threadIdx.x;
  const int lane = tid & 63, w = tid >> 6;
  const int gb = g * 16;

  const int NR = nrung[g];
  for (int i = tid; i <= NR; i += 512) rtab[i] = (unsigned short)runsg[g * 513 + i];

  // ---- B-frag preload: wave w -> gate w>>1, col-half w&1 (16 cols) ----
  const int colb = (w >> 1) * 256 + j * 32 + (w & 1) * 16;
  const int bcol = colb + (lane & 15);
  const int bk8 = (lane >> 4) * 8;
  bf16x8 BH[8], BL[8];
  #pragma unroll
  for (int kc = 0; kc < 8; ++kc) {
    BH[kc] = *(const bf16x8*)(ubh + (size_t)bcol * 256 + kc * 32 + bk8);
    BL[kc] = *(const bf16x8*)(ubl + (size_t)bcol * 256 + kc * 32 + bk8);
  }

  // staging ids
  const int skc = tid >> 6, sl = tid & 63;
  const int sb = sl & 15, sk0 = skc * 32 + (sl >> 4) * 8;
  // activation ids
  const int ab = tid >> 5, ahc = tid & 31;
  const int abs_b = gb + ab, acol = j * 32 + ahc;
  // scatter/f ids
  const bool isf = (w >= 6);
  const int fr0 = (lane >> 4) * 4;
  const int fcl = (w & 1) * 16 + (lane & 15);
  const int colL = (w >> 1) * 32 + (w & 1) * 16 + (lane & 15);
  const int colg = colb + (lane & 15);
  __syncthreads();

  int pa = 0, Lp = 0;
  float xfv[LMAX][4];   // xf gate pre-values for prev-run children (f waves)
  #pragma unroll
  for (int i = 0; i < LMAX; ++i)
    #pragma unroll
    for (int q = 0; q < 4; ++q) xfv[i][q] = 0.f;

  #pragma unroll 1
  for (int r = 0; r < NR; ++r) {
    const int a = rtab[r], b = rtab[r + 1];
    const int L = b - a;

    // ---- 1. ONE combined data-poll for all Lp prev-run blocks ----
    if (r > 0) {
      unsigned long long v[LMAX][4];
      for (;;) {
        #pragma unroll
        for (int i = 0; i < LMAX; ++i) {
          if (i < Lp) {
            const unsigned long long* s64 = (const unsigned long long*)
                (hx + ((size_t)(pa + i) * 8 + g) * 4096 + sb * 256 + sk0);
            v[i][0] = __hip_atomic_load(s64 + 0, RLX, AGT);
            v[i][1] = __hip_atomic_load(s64 + 1, RLX, AGT);
            v[i][2] = __hip_atomic_load(s64 + 2, RLX, AGT);
            v[i][3] = __hip_atomic_load(s64 + 3, RLX, AGT);
          }
        }
        bool ok = true;
        #pragma unroll
        for (int i = 0; i < LMAX; ++i)
          if (i < Lp)
            ok = ok && ok64(v[i][0]) && ok64(v[i][1]) && ok64(v[i][2]) && ok64(v[i][3]);
        if (__all(ok)) break;
      }
      // unpack to AH/AL
      #pragma unroll
      for (int i = 0; i < LMAX; ++i) {
        if (i < Lp) {
          u16x8 hiv, lov;
          #pragma unroll
          for (int q = 0; q < 4; ++q) {
            unsigned lo32 = (unsigned)v[i][q], hi32 = (unsigned)(v[i][q] >> 32);
            hiv[2 * q]     = (unsigned short)(lo32 >> 16);
            lov[2 * q]     = (unsigned short)(lo32 & 0xffffu);
            hiv[2 * q + 1] = (unsigned short)(hi32 >> 16);
            lov[2 * q + 1] = (unsigned short)(hi32 & 0xffffu);
          }
          *(u16x8*)(AH + i * 4096 + skc * 512 + sl * 8) = hiv;
          *(u16x8*)(AL + i * 4096 + skc * 512 + sl * 8) = lov;
        }
      }
    }
    __syncthreads();   // stage barrier: every thread's poll-vmcnt(0) drain ordered

    // ---- 2. post-barrier prefetches (overlap phase B) ----
    // current-run gsum/fcsum rows are FINAL: near scatters of this iter go to LDS,
    // all earlier global scatters drained by each thread's poll + this barrier.
    float gi_[LMAX], go_[LMAX], gu_[LMAX], fp_[LMAX];
    #pragma unroll
    for (int i = 0; i < LMAX; ++i) {
      if (i < L) {
        size_t gio = ((size_t)abs_b * 513 + (a + i)) * 768 + acol;
        gi_[i] = gsum[gio];
        go_[i] = gsum[gio + 256];
        gu_[i] = gsum[gio + 512];
        fp_[i] = fcsum[((size_t)abs_b * 513 + (a + i)) * 256 + acol];
      }
    }
    int patag[LMAX];       // parent tag of prev-run child i for batch ab
    int parp[LMAX][4];     // parents of prev-run child i for this thread's 4 rows
    #pragma unroll
    for (int i = 0; i < LMAX; ++i) {
      patag[i] = (i < Lp) ? parents[abs_b * 512 + (pa + i)] : -1;
      if (i < Lp) {
        #pragma unroll
        for (int q = 0; q < 4; ++q)
          parp[i][q] = parents[(gb + fr0 + q) * 512 + (pa + i)];
      }
    }

    // ---- 3. phase B: prev-run children h @ U; near -> LDS corr, far -> WGP atomic ----
    if (r > 0) {
      #pragma unroll
      for (int i = 0; i < LMAX; ++i) {
        if (i < Lp) {
          f32x4 a0 = {0.f, 0.f, 0.f, 0.f};
          f32x4 a1 = {0.f, 0.f, 0.f, 0.f};
          f32x4 a2 = {0.f, 0.f, 0.f, 0.f};
          #pragma unroll
          for (int kc = 0; kc < 8; ++kc) {
            bf16x8 ah = *(const bf16x8*)(AH + i * 4096 + kc * 512 + lane * 8);
            bf16x8 al = *(const bf16x8*)(AL + i * 4096 + kc * 512 + lane * 8);
            a0 = __builtin_amdgcn_mfma_f32_16x16x32_bf16(ah, BH[kc], a0, 0, 0, 0);
            a1 = __builtin_amdgcn_mfma_f32_16x16x32_bf16(al, BH[kc], a1, 0, 0, 0);
            a2 = __builtin_amdgcn_mfma_f32_16x16x32_bf16(ah, BL[kc], a2, 0, 0, 0);
          }
          f32x4 acc = a0 + a1 + a2;
          if (!isf) {
            #pragma unroll
            for (int q = 0; q < 4; ++q) {
              int rb = fr0 + q, p = parp[i][q];
              if (p < b) gcor[i * 1536 + rb * 96 + colL] = acc[q];
              else __hip_atomic_fetch_add(&gsum[((size_t)(gb + rb) * 513 + p) * 768 + colg],
                                          acc[q], RLX, WGP);
            }
          } else {
            #pragma unroll
            for (int q = 0; q < 4; ++q) {
              int rb = fr0 + q, p = parp[i][q];
              float fg = sigm(xfv[i][q] + acc[q]);
              float fc = fg * cbuf[i * 512 + rb * 32 + fcl];
              if (p < b) fcor[i * 512 + rb * 32 + fcl] = fc;
              else __hip_atomic_fetch_add(&fcsum[((size_t)(gb + rb) * 513 + p) * 256 + j * 32 + fcl],
                                          fc, RLX, WGP);
            }
          }
        }
      }
    }
    __syncthreads();   // corr buffers + cbuf-consumption ordered; NO vmem drain

    // ---- 4. batched activation of current run; tag-gathered corrections; publish ----
    #pragma unroll
    for (int i = 0; i < LMAX; ++i) {
      if (i < L) {
        const int s = a + i;
        float gi = gi_[i], go = go_[i], gu = gu_[i], fct = fp_[i];
        #pragma unroll
        for (int c2 = 0; c2 < LMAX; ++c2) {
          if (c2 < Lp && patag[c2] == s) {
            gi  += gcor[c2 * 1536 + ab * 96 + ahc];
            go  += gcor[c2 * 1536 + ab * 96 + 32 + ahc];
            gu  += gcor[c2 * 1536 + ab * 96 + 64 + ahc];
            fct += fcor[c2 * 512 + ab * 32 + ahc];
          }
        }
        float cval = sigm(gi) * tanh_fast(gu) + fct;
        float h = sigm(go) * tanh_fast(cval);
        cbuf[i * 512 + ab * 32 + ahc] = cval;
        if (s < 511) {
          unsigned short hh = f2bf(h);
          unsigned short hl = f2bf(h - bf2f(hh));
          unsigned packed = ((unsigned)hh << 16) | hl;
          __hip_atomic_store(&hx[((size_t)s * 8 + g) * 4096 + ab * 256 + acol],
                             packed, RLX, AGT);
        }
        out[((size_t)s * 128 + abs_b) * 256 + acol] = h;
        if (s == 511) out[(size_t)512 * 128 * 256 + (size_t)abs_b * 256 + acol] = h;
      }
    }

    // ---- 5. epilogue: xf prefetch for next iteration's phase B (children = current run) ----
    if (isf && r + 1 < NR) {
      #pragma unroll
      for (int i = 0; i < LMAX; ++i) {
        if (i < L) {
          #pragma unroll
          for (int q = 0; q < 4; ++q) {
            int p = parents[(gb + fr0 + q) * 512 + (a + i)];
            xfv[i][q] = (p < 512)
                      ? xf[((size_t)p * 128 + (gb + fr0 + q)) * 256 + j * 32 + fcl] : 0.f;
          }
        }
      }
    }
    pa = a; Lp = L;
  }
}

extern "C" void kernel_launch(void* const* d_in, const int* in_sizes, int n_in,
                              void* d_out, int out_size, void* d_ws, size_t ws_size,
                              hipStream_t stream)
{
  (void)in_sizes; (void)n_in; (void)out_size; (void)ws_size;
  const float* inputs  = (const float*)d_in[0];
  const int*   parents = (const int*)d_in[1];
  const float* Wiou    = (const float*)d_in[2];
  const float* biou    = (const float*)d_in[3];
  const float* Uiou    = (const float*)d_in[4];
  const float* Wf      = (const float*)d_in[5];
  const float* bf_     = (const float*)d_in[6];
  const float* Uf      = (const float*)d_in[7];
  float* out = (float*)d_out;
  char* ws = (char*)d_ws;

  float* fcsum = (float*)(ws + OFF_FCSUM);
  unsigned* hx = (unsigned*)(ws + OFF_HX);
  float* gsum  = (float*)(ws + OFF_GSUM);
  float* xf    = (float*)(ws + OFF_XF);
  unsigned short* bth = (unsigned short*)(ws + OFF_BTH);
  unsigned short* btl = (unsigned short*)(ws + OFF_BTL);
  unsigned short* uh  = (unsigned short*)(ws + OFF_UH);
  unsigned short* ul  = (unsigned short*)(ws + OFF_UL);
  int* runsg = (int*)(ws + OFF_RUNS);
  int* nrung = (int*)(ws + OFF_NRUN);
  unsigned short* ath = (unsigned short*)(ws + OFF_ATH);  // aliases fcsum+hx (pre-gemm only)
  unsigned short* atl = (unsigned short*)(ws + OFF_ATL);

  hipFuncSetAttribute((const void*)gemm_split_kernel,
                      hipFuncAttributeMaxDynamicSharedMemorySize, 65536);
  hipFuncSetAttribute((const void*)scan_kernel,
                      hipFuncAttributeMaxDynamicSharedMemorySize, 134400);

  // Phase 1: precompute bf16 splits + run tables
  cvt_w_kernel<<<2048, 256, 0, stream>>>(Wiou, Wf, bth, btl);
  cvt_u_kernel<<<1024, 256, 0, stream>>>(Uiou, Uf, uh, ul);
  cvt_a_kernel<<<32768, 256, 0, stream>>>(inputs, ath, atl);
  run_kernel<<<8, 512, 0, stream>>>(parents, runsg, nrung);
  // Phase 2: input GEMM
  gemm_split_kernel<<<4096, 256, 65536, stream>>>(ath, atl, bth, btl, biou, bf_, gsum, xf);
  // Phase 3: scan-state init (after gemm frees the alias region)
  hipMemsetAsync(ws + OFF_FCSUM, 0, SZ_FCSUM, stream);
  hipMemsetAsync(ws + OFF_HX, 0xFF, SZ_HX, stream);
  // Phase 4: run-batched scan
  scan_kernel<<<64, 512, 134400, stream>>>(uh, ul, xf, parents, gsum, fcsum, hx,
                                           runsg, nrung, out);
}

// Round 14
// 2623.355 us; speedup vs baseline: 1.1656x; 1.1656x over previous
//
#include <hip/hip_runtime.h>
#include <hip/hip_bf16.h>
#include <cstdint>
#include <cstddef>

#define DI __device__ __forceinline__
#define RLX __ATOMIC_RELAXED
#define AGT __HIP_MEMORY_SCOPE_AGENT
#define WGP __HIP_MEMORY_SCOPE_WORKGROUP

typedef __attribute__((ext_vector_type(8))) short          bf16x8;
typedef __attribute__((ext_vector_type(8))) unsigned short u16x8;
typedef __attribute__((ext_vector_type(4))) unsigned short u16x4;
typedef __attribute__((ext_vector_type(4))) float          f32x4;

// ---- problem constants ----
constexpr int Sv = 512, Bv = 128, Dv = 512, Hv = 256;
constexpr int LMAX = 5;   // run-length cap (LDS-bounded)

// ---- workspace layout (bytes) ----
constexpr size_t SZ_FCSUM  = (size_t)128 * 513 * 256 * 4;            // 67,239,936 (zeroed AFTER gemm)
constexpr size_t OFF_FCSUM = 0;
constexpr size_t OFF_HX    = SZ_FCSUM;                               // poisoned 0xFF AFTER gemm
constexpr size_t SZ_HX     = (size_t)511 * 128 * 256 * 4;            // 66,977,792
constexpr size_t OFF_GSUM  = OFF_HX + SZ_HX;                         // 134,217,728
constexpr size_t SZ_GSUM   = (size_t)128 * 513 * 768 * 4;            // 201,719,808
constexpr size_t OFF_XF    = OFF_GSUM + SZ_GSUM;
constexpr size_t SZ_XF     = (size_t)512 * 128 * 256 * 4;            // 67,108,864
constexpr size_t OFF_BTH   = OFF_XF + SZ_XF;
constexpr size_t OFF_BTL   = OFF_BTH + (size_t)1024 * 512 * 2;
constexpr size_t OFF_UH    = OFF_BTL + (size_t)1024 * 512 * 2;
constexpr size_t OFF_UL    = OFF_UH + (size_t)1024 * 256 * 2;
constexpr size_t OFF_RUNS  = OFF_UL + (size_t)1024 * 256 * 2;        // 8 * 513 ints
constexpr size_t OFF_NRUN  = OFF_RUNS + (size_t)8 * 513 * 4;         // 8 ints
// A pre-split buffers ALIAS the fcsum+hx region (exactly 128 MiB combined).
constexpr size_t OFF_ATH   = 0;
constexpr size_t SZ_ATH    = (size_t)65536 * 512 * 2;                // 67,108,864
constexpr size_t OFF_ATL   = OFF_ATH + SZ_ATH;

// ---- scan LDS layout (bytes) ----
constexpr int LDS_AH   = 0;
constexpr int LDS_AL   = LDS_AH + LMAX * 8192;
constexpr int LDS_GCOR = LDS_AL + LMAX * 8192;          // [LMAX][16][96] f32
constexpr int LDS_FCOR = LDS_GCOR + LMAX * 6144;        // [LMAX][16][32] f32
constexpr int LDS_CBUF = LDS_FCOR + LMAX * 2048;        // [LMAX][16][32] f32
constexpr int LDS_RTAB = LDS_CBUF + LMAX * 2048;        // [513] u16
constexpr int LDS_SCAN = LDS_RTAB + 1040;               // = 134,160 -> 134,400

DI unsigned short f2bf(float x) {  // RNE float->bf16 bits
  union { float f; uint32_t u; } v; v.f = x;
  uint32_t r = v.u + 0x7fffu + ((v.u >> 16) & 1u);
  return (unsigned short)(r >> 16);
}
DI float bf2f(unsigned short b) {
  union { uint32_t u; float f; } v; v.u = ((uint32_t)b) << 16; return v.f;
}
DI float sigm(float x) { return 1.0f / (1.0f + __expf(-x)); }
DI float tanh_fast(float x) {
  float xc = fminf(fmaxf(x, -9.0f), 9.0f);
  float e = __expf(2.0f * xc);
  return (e - 1.0f) / (e + 1.0f);
}
// validity: packed h dword has hh exponent bits[30:23] != 0xFF (|h|<=1 -> exp<=0x7F).
DI bool okd(unsigned d) { return (d & 0x7F800000u) != 0x7F800000u; }
DI bool ok64(unsigned long long v) { return okd((unsigned)v) && okd((unsigned)(v >> 32)); }

// =============== W transpose + bf16 hi/lo split ===============
__global__ void cvt_w_kernel(const float* __restrict__ Wiou, const float* __restrict__ Wf,
                             unsigned short* __restrict__ bth, unsigned short* __restrict__ btl)
{
  int idx = blockIdx.x * 256 + threadIdx.x;
  int n = idx >> 9, k = idx & 511;
  float v = (n < 768) ? Wiou[(size_t)k * 768 + n] : Wf[(size_t)k * 256 + (n - 768)];
  unsigned short h = f2bf(v);
  bth[idx] = h;
  btl[idx] = f2bf(v - bf2f(h));
}

// =============== U -> bf16 hi/lo, [col][k] ===============
__global__ void cvt_u_kernel(const float* __restrict__ Uiou, const float* __restrict__ Uf,
                             unsigned short* __restrict__ uh, unsigned short* __restrict__ ul)
{
  int idx = blockIdx.x * 256 + threadIdx.x;
  int col = idx >> 8, k = idx & 255;
  float v = (col < 768) ? Uiou[(size_t)k * 768 + col] : Uf[(size_t)k * 256 + (col - 768)];
  unsigned short h = f2bf(v);
  uh[idx] = h;
  ul[idx] = f2bf(v - bf2f(h));
}

// =============== A -> bf16 hi/lo ===============
__global__ void cvt_a_kernel(const float* __restrict__ A,
                             unsigned short* __restrict__ ath, unsigned short* __restrict__ atl)
{
  int idx = blockIdx.x * 256 + threadIdx.x;
  f32x4 v = ((const f32x4*)A)[idx];
  u16x4 h, l;
  #pragma unroll
  for (int q = 0; q < 4; ++q) {
    h[q] = f2bf(v[q]);
    l[q] = f2bf(v[q] - bf2f(h[q]));
  }
  ((u16x4*)ath)[idx] = h;
  ((u16x4*)atl)[idx] = l;
}

// =============== run tables (cap LMAX): no intra-run parent edges ===============
__global__ void run_kernel(const int* __restrict__ parents, int* __restrict__ runsg,
                           int* __restrict__ nrung)
{
  __shared__ int pmin[512];
  __shared__ unsigned short rt[513];
  __shared__ int nr_sh;
  const int g = blockIdx.x, tid = threadIdx.x;
  int mn = 1 << 30;
  #pragma unroll
  for (int b = 0; b < 16; ++b) mn = min(mn, parents[(g * 16 + b) * 512 + tid]);
  pmin[tid] = mn;
  __syncthreads();
  if (tid == 0) {
    int r = 0, a = 0;
    while (a < 512) {
      rt[r++] = (unsigned short)a;
      int b = a + 1, m = pmin[a];
      while (b < 512 && (b - a) < LMAX) {
        int m2 = min(m, pmin[b]);
        if (m2 >= b + 1) { m = m2; ++b; } else break;
      }
      a = b;
    }
    rt[r] = 512;
    nr_sh = r;
    nrung[g] = r;
  }
  __syncthreads();
  for (int i = tid; i <= nr_sh; i += 512) runsg[g * 513 + i] = rt[i];
}

// =============== split-bf16 GEMM (R12, verified) ===============
#define GLD_LDS16(gp, lp) __builtin_amdgcn_global_load_lds( \
    (const __attribute__((address_space(1))) unsigned int*)(gp), \
    (__attribute__((address_space(3))) unsigned int*)(lp), 16, 0, 0)

__global__ __launch_bounds__(256, 2)
void gemm_split_kernel(const unsigned short* __restrict__ ATh,
                       const unsigned short* __restrict__ ATl,
                       const unsigned short* __restrict__ BTh,
                       const unsigned short* __restrict__ BTl,
                       const float* __restrict__ biou, const float* __restrict__ bfv,
                       float* __restrict__ gsum, float* __restrict__ xf)
{
  extern __shared__ char lds[];
  unsigned short* As = (unsigned short*)lds;
  unsigned short* Bs = (unsigned short*)(lds + 32768);

  const int bid = blockIdx.x;
  const int ntile = bid & 7, mtile = bid >> 3;
  const int m0 = mtile * 128, n0 = ntile * 128;
  const int tid = threadIdx.x;
  const int lane = tid & 63, w = tid >> 6;
  const int wr = w >> 1, wc = w & 1;

  f32x4 acc[4][4];
  #pragma unroll
  for (int i = 0; i < 4; i++)
    #pragma unroll
    for (int jj = 0; jj < 4; jj++) acc[i][jj] = f32x4{0.f, 0.f, 0.f, 0.f};

  auto stage = [&](unsigned short* dstbase, const unsigned short* src0,
                   int row0, int kk0, int buf) {
    #pragma unroll
    for (int q = 0; q < 4; ++q) {
      int cidx = q * 256 + tid;
      int row = cidx >> 3, blk = cidx & 7;
      const unsigned short* gp = src0 + (size_t)(row0 + row) * 512 + kk0 + blk * 8;
      unsigned short* lp = dstbase + buf * 8192 + cidx * 8;
      GLD_LDS16(gp, lp);
    }
  };

  stage(As, ATh, m0, 0, 0);
  stage(Bs, BTh, n0, 0, 0);
  asm volatile("s_waitcnt vmcnt(0)" ::: "memory");
  __syncthreads();

  for (int t = 0; t < 24; ++t) {
    const int buf = t & 1;
    if (t < 23) {
      const int tn = t + 1;
      stage(As, (tn >= 8 && tn < 16) ? ATl : ATh, m0, (tn & 7) * 64, buf ^ 1);
      stage(Bs, (tn < 16) ? BTh : BTl, n0, (tn & 7) * 64, buf ^ 1);
    }
    #pragma unroll
    for (int kk = 0; kk < 64; kk += 32) {
      const int k8 = (lane >> 4) * 8;
      bf16x8 af[4], bfrag[4];
      #pragma unroll
      for (int mi = 0; mi < 4; ++mi)
        af[mi] = *(const bf16x8*)(As + buf * 8192 + (size_t)(wr * 64 + mi * 16 + (lane & 15)) * 64 + kk + k8);
      #pragma unroll
      for (int ni = 0; ni < 4; ++ni)
        bfrag[ni] = *(const bf16x8*)(Bs + buf * 8192 + (size_t)(wc * 64 + ni * 16 + (lane & 15)) * 64 + kk + k8);
      #pragma unroll
      for (int mi = 0; mi < 4; ++mi)
        #pragma unroll
        for (int ni = 0; ni < 4; ++ni)
          acc[mi][ni] = __builtin_amdgcn_mfma_f32_16x16x32_bf16(af[mi], bfrag[ni], acc[mi][ni], 0, 0, 0);
    }
    asm volatile("s_waitcnt vmcnt(0)" ::: "memory");
    __syncthreads();
  }

  const bool isiou = (n0 < 768);
  const int s_ = mtile;
  #pragma unroll
  for (int ni = 0; ni < 4; ++ni) {
    int coln = n0 + wc * 64 + ni * 16 + (lane & 15);
    float bv = isiou ? biou[coln] : bfv[coln - 768];
    #pragma unroll
    for (int mi = 0; mi < 4; ++mi)
      #pragma unroll
      for (int r = 0; r < 4; ++r) {
        int bg = wr * 64 + mi * 16 + (lane >> 4) * 4 + r;
        float v = acc[mi][ni][r] + bv;
        if (isiou) gsum[((size_t)bg * 513 + s_) * 768 + coln] = v;
        else       xf[((size_t)s_ * 128 + bg) * 256 + (coln - 768)] = v;
      }
  }
}

// =============== scan by RUNS v3: CANARY poll + manual release ordering ===============
// Publisher: publish nodes 0..L-2 relaxed -> s_waitcnt vmcnt(0) (all prior MALL
// stores complete) -> publish node L-1 (canary). Consumer: poll ONLY the canary
// block (4 u64, R12-proven cost); canary validity implies the same 8 producer
// threads' earlier-node cells are visible -> read remaining blocks WITHOUT polling.
// out stores + xf prefetch issue after the canary publish (off the publish path).
__global__ __launch_bounds__(512, 1)
void scan_kernel(const unsigned short* __restrict__ ubh, const unsigned short* __restrict__ ubl,
                 const float* __restrict__ xf, const int* __restrict__ parents,
                 float* gsum, float* fcsum, unsigned* hx,
                 const int* __restrict__ runsg, const int* __restrict__ nrung,
                 float* __restrict__ out)
{
  extern __shared__ char lds[];
  unsigned short* AH   = (unsigned short*)(lds + LDS_AH);    // [LMAX][4096]
  unsigned short* AL   = (unsigned short*)(lds + LDS_AL);    // [LMAX][4096]
  float*          gcor = (float*)(lds + LDS_GCOR);           // [LMAX][16][96] child-indexed
  float*          fcor = (float*)(lds + LDS_FCOR);           // [LMAX][16][32]
  float*          cbuf = (float*)(lds + LDS_CBUF);           // [LMAX][16][32]
  unsigned short* rtab = (unsigned short*)(lds + LDS_RTAB);  // [513]

  const int bid = blockIdx.x;
  const int g = bid & 7, j = bid >> 3;
  const int tid = threadIdx.x;
  const int lane = tid & 63, w = tid >> 6;
  const int gb = g * 16;

  const int NR = nrung[g];
  for (int i = tid; i <= NR; i += 512) rtab[i] = (unsigned short)runsg[g * 513 + i];

  // ---- B-frag preload: wave w -> gate w>>1, col-half w&1 (16 cols) ----
  const int colb = (w >> 1) * 256 + j * 32 + (w & 1) * 16;
  const int bcol = colb + (lane & 15);
  const int bk8 = (lane >> 4) * 8;
  bf16x8 BH[8], BL[8];
  #pragma unroll
  for (int kc = 0; kc < 8; ++kc) {
    BH[kc] = *(const bf16x8*)(ubh + (size_t)bcol * 256 + kc * 32 + bk8);
    BL[kc] = *(const bf16x8*)(ubl + (size_t)bcol * 256 + kc * 32 + bk8);
  }

  // staging ids
  const int skc = tid >> 6, sl = tid & 63;
  const int sb = sl & 15, sk0 = skc * 32 + (sl >> 4) * 8;
  // activation ids
  const int ab = tid >> 5, ahc = tid & 31;
  const int abs_b = gb + ab, acol = j * 32 + ahc;
  // scatter/f ids
  const bool isf = (w >= 6);
  const int fr0 = (lane >> 4) * 4;
  const int fcl = (w & 1) * 16 + (lane & 15);
  const int colL = (w >> 1) * 32 + (w & 1) * 16 + (lane & 15);
  const int colg = colb + (lane & 15);
  __syncthreads();

  int pa = 0, Lp = 0;
  float xfv[LMAX][4];
  #pragma unroll
  for (int i = 0; i < LMAX; ++i)
    #pragma unroll
    for (int q = 0; q < 4; ++q) xfv[i][q] = 0.f;

  #pragma unroll 1
  for (int r = 0; r < NR; ++r) {
    const int a = rtab[r], b = rtab[r + 1];
    const int L = b - a;

    // ---- 1. CANARY poll (last block only; 4 u64 like R12), then read the rest ----
    if (r > 0) {
      const int cbk = Lp - 1;
      const unsigned long long* c64 = (const unsigned long long*)
          (hx + ((size_t)(pa + cbk) * 8 + g) * 4096 + sb * 256 + sk0);
      unsigned long long c0, c1, c2, c3;
      for (;;) {
        c0 = __hip_atomic_load(c64 + 0, RLX, AGT);
        c1 = __hip_atomic_load(c64 + 1, RLX, AGT);
        c2 = __hip_atomic_load(c64 + 2, RLX, AGT);
        c3 = __hip_atomic_load(c64 + 3, RLX, AGT);
        if (ok64(c0) && ok64(c1) && ok64(c2) && ok64(c3)) break;
      }
      asm volatile("" ::: "memory");   // no hoisting of the follow-up loads above the poll
      unsigned long long vv[LMAX][4];
      vv[cbk][0] = c0; vv[cbk][1] = c1; vv[cbk][2] = c2; vv[cbk][3] = c3;
      #pragma unroll
      for (int i = 0; i < LMAX; ++i) {
        if (i < cbk) {
          const unsigned long long* s64 = (const unsigned long long*)
              (hx + ((size_t)(pa + i) * 8 + g) * 4096 + sb * 256 + sk0);
          vv[i][0] = __hip_atomic_load(s64 + 0, RLX, AGT);
          vv[i][1] = __hip_atomic_load(s64 + 1, RLX, AGT);
          vv[i][2] = __hip_atomic_load(s64 + 2, RLX, AGT);
          vv[i][3] = __hip_atomic_load(s64 + 3, RLX, AGT);
        }
      }
      #pragma unroll
      for (int i = 0; i < LMAX; ++i) {
        if (i < Lp) {
          u16x8 hiv, lov;
          #pragma unroll
          for (int q = 0; q < 4; ++q) {
            unsigned lo32 = (unsigned)vv[i][q], hi32 = (unsigned)(vv[i][q] >> 32);
            hiv[2 * q]     = (unsigned short)(lo32 >> 16);
            lov[2 * q]     = (unsigned short)(lo32 & 0xffffu);
            hiv[2 * q + 1] = (unsigned short)(hi32 >> 16);
            lov[2 * q + 1] = (unsigned short)(hi32 & 0xffffu);
          }
          *(u16x8*)(AH + i * 4096 + skc * 512 + sl * 8) = hiv;
          *(u16x8*)(AL + i * 4096 + skc * 512 + sl * 8) = lov;
        }
      }
    }
    __syncthreads();   // stage barrier

    // ---- 2. post-barrier prefetches (overlap phase B); current-run rows are FINAL ----
    float gi_[LMAX], go_[LMAX], gu_[LMAX], fp_[LMAX];
    #pragma unroll
    for (int i = 0; i < LMAX; ++i) {
      if (i < L) {
        size_t gio = ((size_t)abs_b * 513 + (a + i)) * 768 + acol;
        gi_[i] = gsum[gio];
        go_[i] = gsum[gio + 256];
        gu_[i] = gsum[gio + 512];
        fp_[i] = fcsum[((size_t)abs_b * 513 + (a + i)) * 256 + acol];
      }
    }
    int patag[LMAX];
    int parp[LMAX][4];
    #pragma unroll
    for (int i = 0; i < LMAX; ++i) {
      patag[i] = (i < Lp) ? parents[abs_b * 512 + (pa + i)] : -1;
      if (i < Lp) {
        #pragma unroll
        for (int q = 0; q < 4; ++q)
          parp[i][q] = parents[(gb + fr0 + q) * 512 + (pa + i)];
      }
    }

    // ---- 3. phase B: prev-run children h @ U; near (p<b) -> LDS corr, far -> WGP atomic ----
    if (r > 0) {
      #pragma unroll
      for (int i = 0; i < LMAX; ++i) {
        if (i < Lp) {
          f32x4 a0 = {0.f, 0.f, 0.f, 0.f};
          f32x4 a1 = {0.f, 0.f, 0.f, 0.f};
          f32x4 a2 = {0.f, 0.f, 0.f, 0.f};
          #pragma unroll
          for (int kc = 0; kc < 8; ++kc) {
            bf16x8 ah = *(const bf16x8*)(AH + i * 4096 + kc * 512 + lane * 8);
            bf16x8 al = *(const bf16x8*)(AL + i * 4096 + kc * 512 + lane * 8);
            a0 = __builtin_amdgcn_mfma_f32_16x16x32_bf16(ah, BH[kc], a0, 0, 0, 0);
            a1 = __builtin_amdgcn_mfma_f32_16x16x32_bf16(al, BH[kc], a1, 0, 0, 0);
            a2 = __builtin_amdgcn_mfma_f32_16x16x32_bf16(ah, BL[kc], a2, 0, 0, 0);
          }
          f32x4 acc = a0 + a1 + a2;
          if (!isf) {
            #pragma unroll
            for (int q = 0; q < 4; ++q) {
              int rb = fr0 + q, p = parp[i][q];
              if (p < b) gcor[i * 1536 + rb * 96 + colL] = acc[q];
              else __hip_atomic_fetch_add(&gsum[((size_t)(gb + rb) * 513 + p) * 768 + colg],
                                          acc[q], RLX, WGP);
            }
          } else {
            #pragma unroll
            for (int q = 0; q < 4; ++q) {
              int rb = fr0 + q, p = parp[i][q];
              float fg = sigm(xfv[i][q] + acc[q]);
              float fc = fg * cbuf[i * 512 + rb * 32 + fcl];
              if (p < b) fcor[i * 512 + rb * 32 + fcl] = fc;
              else __hip_atomic_fetch_add(&fcsum[((size_t)(gb + rb) * 513 + p) * 256 + j * 32 + fcl],
                                          fc, RLX, WGP);
            }
          }
        }
      }
    }
    __syncthreads();   // corr buffers + cbuf ordered; no vmem drain

    // ---- 4. batched activation; publish 0..L-2 relaxed -> drain -> canary ----
    float hval[LMAX];
    unsigned pk[LMAX];
    #pragma unroll
    for (int i = 0; i < LMAX; ++i) {
      if (i < L) {
        const int s = a + i;
        float gi = gi_[i], go = go_[i], gu = gu_[i], fct = fp_[i];
        #pragma unroll
        for (int c2 = 0; c2 < LMAX; ++c2) {
          if (c2 < Lp && patag[c2] == s) {
            gi  += gcor[c2 * 1536 + ab * 96 + ahc];
            go  += gcor[c2 * 1536 + ab * 96 + 32 + ahc];
            gu  += gcor[c2 * 1536 + ab * 96 + 64 + ahc];
            fct += fcor[c2 * 512 + ab * 32 + ahc];
          }
        }
        float cval = sigm(gi) * tanh_fast(gu) + fct;
        float h = sigm(go) * tanh_fast(cval);
        cbuf[i * 512 + ab * 32 + ahc] = cval;
        hval[i] = h;
        unsigned short hh = f2bf(h);
        unsigned short hl = f2bf(h - bf2f(hh));
        pk[i] = ((unsigned)hh << 16) | hl;
        if (i < L - 1 && s < 511)    // non-canary publishes (relaxed)
          __hip_atomic_store(&hx[((size_t)s * 8 + g) * 4096 + ab * 256 + acol],
                             pk[i], RLX, AGT);
      }
    }
    {
      const int s_last = a + L - 1;
      if (s_last < 511) {
        // manual release: all prior MALL stores complete before the canary issues
        asm volatile("s_waitcnt vmcnt(0)" ::: "memory");
        __hip_atomic_store(&hx[((size_t)s_last * 8 + g) * 4096 + ab * 256 + acol],
                           pk[L - 1], RLX, AGT);
      }
    }
    // out stores AFTER the canary (off the publish critical path)
    #pragma unroll
    for (int i = 0; i < LMAX; ++i) {
      if (i < L) {
        const int s = a + i;
        out[((size_t)s * 128 + abs_b) * 256 + acol] = hval[i];
        if (s == 511) out[(size_t)512 * 128 * 256 + (size_t)abs_b * 256 + acol] = hval[i];
      }
    }

    // ---- 5. epilogue: xf prefetch for next iteration's phase B ----
    if (isf && r + 1 < NR) {
      #pragma unroll
      for (int i = 0; i < LMAX; ++i) {
        if (i < L) {
          #pragma unroll
          for (int q = 0; q < 4; ++q) {
            int p = parents[(gb + fr0 + q) * 512 + (a + i)];
            xfv[i][q] = (p < 512)
                      ? xf[((size_t)p * 128 + (gb + fr0 + q)) * 256 + j * 32 + fcl] : 0.f;
          }
        }
      }
    }
    pa = a; Lp = L;
  }
}

extern "C" void kernel_launch(void* const* d_in, const int* in_sizes, int n_in,
                              void* d_out, int out_size, void* d_ws, size_t ws_size,
                              hipStream_t stream)
{
  (void)in_sizes; (void)n_in; (void)out_size; (void)ws_size;
  const float* inputs  = (const float*)d_in[0];
  const int*   parents = (const int*)d_in[1];
  const float* Wiou    = (const float*)d_in[2];
  const float* biou    = (const float*)d_in[3];
  const float* Uiou    = (const float*)d_in[4];
  const float* Wf      = (const float*)d_in[5];
  const float* bf_     = (const float*)d_in[6];
  const float* Uf      = (const float*)d_in[7];
  float* out = (float*)d_out;
  char* ws = (char*)d_ws;

  float* fcsum = (float*)(ws + OFF_FCSUM);
  unsigned* hx = (unsigned*)(ws + OFF_HX);
  float* gsum  = (float*)(ws + OFF_GSUM);
  float* xf    = (float*)(ws + OFF_XF);
  unsigned short* bth = (unsigned short*)(ws + OFF_BTH);
  unsigned short* btl = (unsigned short*)(ws + OFF_BTL);
  unsigned short* uh  = (unsigned short*)(ws + OFF_UH);
  unsigned short* ul  = (unsigned short*)(ws + OFF_UL);
  int* runsg = (int*)(ws + OFF_RUNS);
  int* nrung = (int*)(ws + OFF_NRUN);
  unsigned short* ath = (unsigned short*)(ws + OFF_ATH);  // aliases fcsum+hx (pre-gemm only)
  unsigned short* atl = (unsigned short*)(ws + OFF_ATL);

  hipFuncSetAttribute((const void*)gemm_split_kernel,
                      hipFuncAttributeMaxDynamicSharedMemorySize, 65536);
  hipFuncSetAttribute((const void*)scan_kernel,
                      hipFuncAttributeMaxDynamicSharedMemorySize, 134400);

  // Phase 1: precompute bf16 splits + run tables
  cvt_w_kernel<<<2048, 256, 0, stream>>>(Wiou, Wf, bth, btl);
  cvt_u_kernel<<<1024, 256, 0, stream>>>(Uiou, Uf, uh, ul);
  cvt_a_kernel<<<32768, 256, 0, stream>>>(inputs, ath, atl);
  run_kernel<<<8, 512, 0, stream>>>(parents, runsg, nrung);
  // Phase 2: input GEMM
  gemm_split_kernel<<<4096, 256, 65536, stream>>>(ath, atl, bth, btl, biou, bf_, gsum, xf);
  // Phase 3: scan-state init (after gemm frees the alias region)
  hipMemsetAsync(ws + OFF_FCSUM, 0, SZ_FCSUM, stream);
  hipMemsetAsync(ws + OFF_HX, 0xFF, SZ_HX, stream);
  // Phase 4: run-batched scan (canary-poll)
  scan_kernel<<<64, 512, 134400, stream>>>(uh, ul, xf, parents, gsum, fcsum, hx,
                                           runsg, nrung, out);
}

// Round 16
// 1972.623 us; speedup vs baseline: 1.5501x; 1.3299x over previous
//
#include <hip/hip_runtime.h>
#include <hip/hip_bf16.h>
#include <cstdint>
#include <cstddef>

#define DI __device__ __forceinline__
#define RLX __ATOMIC_RELAXED
#define AGT __HIP_MEMORY_SCOPE_AGENT
#define WGP __HIP_MEMORY_SCOPE_WORKGROUP

typedef __attribute__((ext_vector_type(8))) short          bf16x8;
typedef __attribute__((ext_vector_type(8))) unsigned short u16x8;
typedef __attribute__((ext_vector_type(4))) unsigned short u16x4;
typedef __attribute__((ext_vector_type(4))) float          f32x4;

// ---- problem constants ----
constexpr int Sv = 512, Bv = 128, Dv = 512, Hv = 256;

// ---- workspace layout (bytes) ----
constexpr size_t SZ_FCSUM  = (size_t)128 * 513 * 256 * 4;            // 67,239,936 (zeroed AFTER gemm)
constexpr size_t OFF_FCSUM = 0;
constexpr size_t OFF_HX    = SZ_FCSUM;                               // poisoned 0xFF AFTER gemm
constexpr size_t SZ_HX     = (size_t)511 * 128 * 256 * 4;            // 66,977,792
constexpr size_t OFF_GSUM  = OFF_HX + SZ_HX;                         // 134,217,728
constexpr size_t SZ_GSUM   = (size_t)128 * 513 * 768 * 4;            // 201,719,808
constexpr size_t OFF_XF    = OFF_GSUM + SZ_GSUM;
constexpr size_t SZ_XF     = (size_t)512 * 128 * 256 * 4;            // 67,108,864
constexpr size_t OFF_BTH   = OFF_XF + SZ_XF;
constexpr size_t OFF_BTL   = OFF_BTH + (size_t)1024 * 512 * 2;
constexpr size_t OFF_UH    = OFF_BTL + (size_t)1024 * 512 * 2;
constexpr size_t OFF_UL    = OFF_UH + (size_t)1024 * 256 * 2;
// A pre-split buffers ALIAS the fcsum+hx region (exactly 128 MiB combined).
// Live only from cvt_a to end of gemm; the fcsum/hx memsets run after.
constexpr size_t OFF_ATH   = 0;
constexpr size_t SZ_ATH    = (size_t)65536 * 512 * 2;                // 67,108,864
constexpr size_t OFF_ATL   = OFF_ATH + SZ_ATH;

DI unsigned short f2bf(float x) {  // RNE float->bf16 bits
  union { float f; uint32_t u; } v; v.f = x;
  uint32_t r = v.u + 0x7fffu + ((v.u >> 16) & 1u);
  return (unsigned short)(r >> 16);
}
DI float bf2f(unsigned short b) {
  union { uint32_t u; float f; } v; v.u = ((uint32_t)b) << 16; return v.f;
}
DI float sigm(float x) { return 1.0f / (1.0f + __expf(-x)); }
DI float tanh_fast(float x) {   // clamp + rational exp: |err| ~1e-7, no branches
  float xc = fminf(fmaxf(x, -9.0f), 9.0f);
  float e = __expf(2.0f * xc);
  return (e - 1.0f) / (e + 1.0f);
}
// validity: packed h dword has exponent bits[30:23] != 0xFF (|h|<=1 -> exp<=0x7F).
DI bool okd(unsigned d) { return (d & 0x7F800000u) != 0x7F800000u; }
DI bool ok64(unsigned long long v) { return okd((unsigned)v) && okd((unsigned)(v >> 32)); }

// =============== W transpose + bf16 hi/lo split: BT[n][k], n in [0,1024) ===============
__global__ void cvt_w_kernel(const float* __restrict__ Wiou, const float* __restrict__ Wf,
                             unsigned short* __restrict__ bth, unsigned short* __restrict__ btl)
{
  int idx = blockIdx.x * 256 + threadIdx.x;  // 1024*512
  int n = idx >> 9, k = idx & 511;
  float v = (n < 768) ? Wiou[(size_t)k * 768 + n] : Wf[(size_t)k * 256 + (n - 768)];
  unsigned short h = f2bf(v);
  bth[idx] = h;
  btl[idx] = f2bf(v - bf2f(h));
}

// =============== U -> bf16 hi/lo, [col][k] layout for B-fragment loads ===============
__global__ void cvt_u_kernel(const float* __restrict__ Uiou, const float* __restrict__ Uf,
                             unsigned short* __restrict__ uh, unsigned short* __restrict__ ul)
{
  int idx = blockIdx.x * 256 + threadIdx.x;  // 1024 cols * 256 k
  int col = idx >> 8, k = idx & 255;
  float v = (col < 768) ? Uiou[(size_t)k * 768 + col] : Uf[(size_t)k * 256 + (col - 768)];
  unsigned short h = f2bf(v);
  uh[idx] = h;
  ul[idx] = f2bf(v - bf2f(h));
}

// =============== A -> bf16 hi/lo, row-major [m][k] (vectorized x4) ===============
__global__ void cvt_a_kernel(const float* __restrict__ A,
                             unsigned short* __restrict__ ath, unsigned short* __restrict__ atl)
{
  int idx = blockIdx.x * 256 + threadIdx.x;   // 8,388,608 threads x 4 elems
  f32x4 v = ((const f32x4*)A)[idx];
  u16x4 h, l;
  #pragma unroll
  for (int q = 0; q < 4; ++q) {
    h[q] = f2bf(v[q]);
    l[q] = f2bf(v[q] - bf2f(h[q]));
  }
  ((u16x4*)ath)[idx] = h;
  ((u16x4*)atl)[idx] = l;
}

// =============== 3-term split-bf16 GEMM (R12, verified fp32-accurate) ===============
// tiles t 0-7 (Ah,Bh); 8-15 (Al,Bh); 16-23 (Ah,Bl); k0 = (t&7)*64.
#define GLD_LDS16(gp, lp) __builtin_amdgcn_global_load_lds( \
    (const __attribute__((address_space(1))) unsigned int*)(gp), \
    (__attribute__((address_space(3))) unsigned int*)(lp), 16, 0, 0)

__global__ __launch_bounds__(256, 2)
void gemm_split_kernel(const unsigned short* __restrict__ ATh,
                       const unsigned short* __restrict__ ATl,
                       const unsigned short* __restrict__ BTh,
                       const unsigned short* __restrict__ BTl,
                       const float* __restrict__ biou, const float* __restrict__ bfv,
                       float* __restrict__ gsum, float* __restrict__ xf)
{
  extern __shared__ char lds[];
  unsigned short* As = (unsigned short*)lds;             // [2][128][64]
  unsigned short* Bs = (unsigned short*)(lds + 32768);   // [2][128][64]

  const int bid = blockIdx.x;
  const int ntile = bid & 7, mtile = bid >> 3;
  const int m0 = mtile * 128, n0 = ntile * 128;
  const int tid = threadIdx.x;
  const int lane = tid & 63, w = tid >> 6;
  const int wr = w >> 1, wc = w & 1;

  f32x4 acc[4][4];
  #pragma unroll
  for (int i = 0; i < 4; i++)
    #pragma unroll
    for (int jj = 0; jj < 4; jj++) acc[i][jj] = f32x4{0.f, 0.f, 0.f, 0.f};

  auto stage = [&](unsigned short* dstbase, const unsigned short* src0,
                   int row0, int kk0, int buf) {
    #pragma unroll
    for (int q = 0; q < 4; ++q) {
      int cidx = q * 256 + tid;
      int row = cidx >> 3, blk = cidx & 7;
      const unsigned short* gp = src0 + (size_t)(row0 + row) * 512 + kk0 + blk * 8;
      unsigned short* lp = dstbase + buf * 8192 + cidx * 8;
      GLD_LDS16(gp, lp);
    }
  };

  stage(As, ATh, m0, 0, 0);
  stage(Bs, BTh, n0, 0, 0);
  asm volatile("s_waitcnt vmcnt(0)" ::: "memory");
  __syncthreads();

  for (int t = 0; t < 24; ++t) {
    const int buf = t & 1;
    if (t < 23) {
      const int tn = t + 1;
      stage(As, (tn >= 8 && tn < 16) ? ATl : ATh, m0, (tn & 7) * 64, buf ^ 1);
      stage(Bs, (tn < 16) ? BTh : BTl, n0, (tn & 7) * 64, buf ^ 1);
    }
    #pragma unroll
    for (int kk = 0; kk < 64; kk += 32) {
      const int k8 = (lane >> 4) * 8;
      bf16x8 af[4], bfrag[4];
      #pragma unroll
      for (int mi = 0; mi < 4; ++mi)
        af[mi] = *(const bf16x8*)(As + buf * 8192 + (size_t)(wr * 64 + mi * 16 + (lane & 15)) * 64 + kk + k8);
      #pragma unroll
      for (int ni = 0; ni < 4; ++ni)
        bfrag[ni] = *(const bf16x8*)(Bs + buf * 8192 + (size_t)(wc * 64 + ni * 16 + (lane & 15)) * 64 + kk + k8);
      #pragma unroll
      for (int mi = 0; mi < 4; ++mi)
        #pragma unroll
        for (int ni = 0; ni < 4; ++ni)
          acc[mi][ni] = __builtin_amdgcn_mfma_f32_16x16x32_bf16(af[mi], bfrag[ni], acc[mi][ni], 0, 0, 0);
    }
    asm volatile("s_waitcnt vmcnt(0)" ::: "memory");
    __syncthreads();
  }

  const bool isiou = (n0 < 768);  // block-uniform
  const int s_ = mtile;           // one s per m-tile (128 rows = all batches)
  #pragma unroll
  for (int ni = 0; ni < 4; ++ni) {
    int coln = n0 + wc * 64 + ni * 16 + (lane & 15);
    float bv = isiou ? biou[coln] : bfv[coln - 768];
    #pragma unroll
    for (int mi = 0; mi < 4; ++mi)
      #pragma unroll
      for (int r = 0; r < 4; ++r) {
        int bg = wr * 64 + mi * 16 + (lane >> 4) * 4 + r;
        float v = acc[mi][ni][r] + bv;
        if (isiou) gsum[((size_t)bg * 513 + s_) * 768 + coln] = v;
        else       xf[((size_t)s_ * 128 + bg) * 256 + (coln - 768)] = v;
      }
  }
}

// =============== scan (R12 structure, 2-term: bf16(h) @ (Uh+Ul)) ===============
// Data-poll exchange (no flags, hang-safe): h published per-step into poisoned hx
// slots; readers poll the data itself. gsum/fcsum/xf wg-private (WGP atomics, plain
// prefetch loads). vs R12: h-lo path deleted (publish hi only, 16 MFMA not 24);
// dropped hl@U term sigma ~5e-4 -- the GEMM's Al@B term (the dominant R15 error)
// is restored above.
__global__ __launch_bounds__(512, 1)
void scan_kernel(const unsigned short* __restrict__ ubh, const unsigned short* __restrict__ ubl,
                 const float* __restrict__ xf, const int* __restrict__ parents,
                 float* gsum, float* fcsum, unsigned* hx,
                 float* __restrict__ out)
{
  __shared__ __align__(16) unsigned short AH[8 * 64 * 8];   // A-frags hi: [kc][lane][8]
  __shared__ float gcor[16 * 96];
  __shared__ float fcor[16 * 32];
  __shared__ float cbuf[16 * 32];
  __shared__ int   pbuf[2][16];
  __shared__ int   pl[16];

  const int bid = blockIdx.x;
  const int g = bid & 7, j = bid >> 3;   // group members share bid%8
  const int tid = threadIdx.x;
  const int lane = tid & 63, w = tid >> 6;
  const int gb = g * 16;

  // ---- B-frag preload: wave w -> gate w>>1, col-half w&1 (16 cols) ----
  const int colb = (w >> 1) * 256 + j * 32 + (w & 1) * 16;
  const int bcol = colb + (lane & 15);
  const int bk8 = (lane >> 4) * 8;
  bf16x8 BH[8], BL[8];
  #pragma unroll
  for (int kc = 0; kc < 8; ++kc) {
    BH[kc] = *(const bf16x8*)(ubh + (size_t)bcol * 256 + kc * 32 + bk8);
    BL[kc] = *(const bf16x8*)(ubl + (size_t)bcol * 256 + kc * 32 + bk8);
  }

  // staging ids: thread -> (kc, lane-slot) -> (batch, k0)
  const int skc = tid >> 6, sl = tid & 63;
  const int sb = sl & 15, sk0 = skc * 32 + (sl >> 4) * 8;
  // activation ids
  const int ab = tid >> 5, ahc = tid & 31;
  const int abs_b = gb + ab, acol = j * 32 + ahc;
  // f ids
  const bool isf = (w >= 6);
  const int fr0 = (lane >> 4) * 4;
  const int fcl = (w & 1) * 16 + (lane & 15);

  if (tid < 16) { pbuf[0][tid] = parents[(gb + tid) * 512]; pl[tid] = -1; }

  float pre_i, pre_o, pre_u, fct_pre;
  {
    size_t gi0 = ((size_t)abs_b * 513) * 768 + acol;
    pre_i = gsum[gi0];
    pre_o = gsum[gi0 + 256];
    pre_u = gsum[gi0 + 512];
    fct_pre = fcsum[((size_t)abs_b * 513) * 256 + acol];
  }
  float xfv[4] = {0.f, 0.f, 0.f, 0.f};
  __syncthreads();

  #pragma unroll 1
  for (int s = 0; s < 512; ++s) {
    // ---- stage h(s-1): DATA-POLL per-step slot, unpack hi-bf16 to AH frag layout ----
    if (s > 0) {
      const unsigned long long* s64 =
          (const unsigned long long*)(hx + ((size_t)(s - 1) * 8 + g) * 4096 + sb * 256 + sk0);
      unsigned long long v0, v1, v2, v3;
      for (;;) {
        v0 = __hip_atomic_load(s64 + 0, RLX, AGT);
        v1 = __hip_atomic_load(s64 + 1, RLX, AGT);
        v2 = __hip_atomic_load(s64 + 2, RLX, AGT);
        v3 = __hip_atomic_load(s64 + 3, RLX, AGT);
        if (ok64(v0) && ok64(v1) && ok64(v2) && ok64(v3)) break;
      }
      u16x8 hiv;
      unsigned long long vv[4] = {v0, v1, v2, v3};
      #pragma unroll
      for (int q = 0; q < 4; ++q) {
        unsigned lo32 = (unsigned)vv[q], hi32 = (unsigned)(vv[q] >> 32);
        hiv[2 * q]     = (unsigned short)(lo32 >> 16);
        hiv[2 * q + 1] = (unsigned short)(hi32 >> 16);
      }
      *(u16x8*)(AH + skc * 512 + sl * 8) = hiv;
    }
    __syncthreads();   // stage barrier

    // ---- phase B: bf16(h(s-1)) @ (Uh+Ul) (all 4 gates, 2 independent MFMA chains) ----
    if (s > 0) {
      f32x4 a0 = {0.f, 0.f, 0.f, 0.f};
      f32x4 a2 = {0.f, 0.f, 0.f, 0.f};
      #pragma unroll
      for (int kc = 0; kc < 8; ++kc) {
        bf16x8 ah = *(const bf16x8*)(AH + kc * 512 + lane * 8);
        a0 = __builtin_amdgcn_mfma_f32_16x16x32_bf16(ah, BH[kc], a0, 0, 0, 0);
        a2 = __builtin_amdgcn_mfma_f32_16x16x32_bf16(ah, BL[kc], a2, 0, 0, 0);
      }
      f32x4 acc = a0 + a2;
      if (!isf) {
        const int colg = colb + (lane & 15);
        const int colL = (w >> 1) * 32 + (w & 1) * 16 + (lane & 15);
        #pragma unroll
        for (int r = 0; r < 4; ++r) {
          int rb = fr0 + r;
          int p = pbuf[(s - 1) & 1][rb];
          if (p == s) gcor[rb * 96 + colL] = acc[r];
          else __hip_atomic_fetch_add(&gsum[((size_t)(gb + rb) * 513 + p) * 768 + colg],
                                      acc[r], RLX, WGP);   // wg-private: local-L2 atomic
        }
      } else {
        #pragma unroll
        for (int r = 0; r < 4; ++r) {
          int rb = fr0 + r;
          int p = pbuf[(s - 1) & 1][rb];
          float fg = sigm(xfv[r] + acc[r]);
          float fc = fg * cbuf[rb * 32 + fcl];
          if (p == s) fcor[rb * 32 + fcl] = fc;
          else __hip_atomic_fetch_add(&fcsum[((size_t)(gb + rb) * 513 + p) * 256 + j * 32 + fcl],
                                      fc, RLX, WGP);       // wg-private: local-L2 atomic
        }
        if (w == 6 && (lane & 15) == 0) {
          #pragma unroll
          for (int r = 0; r < 4; ++r) pl[fr0 + r] = pbuf[(s - 1) & 1][fr0 + r];
        }
      }
    }

    // ---- drain scatters (wg-local), then barrier: orders scatters/gcor/pl vs below ----
    asm volatile("s_waitcnt vmcnt(0)" ::: "memory");
    __syncthreads();

    // ---- activation for node s (all 512 threads: 16 b x 32 hc); publish h FIRST ----
    {
      bool corr = (pl[ab] == s);
      float gi = pre_i + (corr ? gcor[ab * 96 + ahc] : 0.f);
      float go = pre_o + (corr ? gcor[ab * 96 + 32 + ahc] : 0.f);
      float gu = pre_u + (corr ? gcor[ab * 96 + 64 + ahc] : 0.f);
      float fct = fct_pre + (corr ? fcor[ab * 32 + ahc] : 0.f);
      float c = sigm(gi) * tanh_fast(gu) + fct;
      float h = sigm(go) * tanh_fast(c);
      if (s < 511) {
        unsigned packed = ((unsigned)f2bf(h)) << 16;   // hi bf16 only; exp<=0x7F = valid
        __hip_atomic_store(&hx[((size_t)s * 8 + g) * 4096 + ab * 256 + acol],
                           packed, RLX, AGT);   // coherence point: readers data-poll this
      }
      cbuf[ab * 32 + ahc] = c;
      out[((size_t)s * 128 + abs_b) * 256 + acol] = h;
      if (s == 511) out[(size_t)512 * 128 * 256 + (size_t)abs_b * 256 + acol] = h;
    }

    // ---- prefetch row s+1 (wg-private; ordered after this step's scatters by the
    //      drain barrier above) — overlaps the next stage poll ----
    if (s < 511) {
      const int sn = s + 1;
      {
        size_t gi1 = ((size_t)abs_b * 513 + sn) * 768 + acol;
        pre_i = gsum[gi1];
        pre_o = gsum[gi1 + 256];
        pre_u = gsum[gi1 + 512];
        fct_pre = fcsum[((size_t)abs_b * 513 + sn) * 256 + acol];
      }
      if (tid < 16) pbuf[sn & 1][tid] = parents[(gb + tid) * 512 + sn];
      if (isf) {
        #pragma unroll
        for (int r = 0; r < 4; ++r) {
          int p = pbuf[s & 1][fr0 + r];   // parents[.][s], loaded last iteration
          xfv[r] = (p < 512) ? xf[((size_t)p * 128 + (gb + fr0 + r)) * 256 + j * 32 + fcl] : 0.f;
        }
      }
    }
  }
}

extern "C" void kernel_launch(void* const* d_in, const int* in_sizes, int n_in,
                              void* d_out, int out_size, void* d_ws, size_t ws_size,
                              hipStream_t stream)
{
  (void)in_sizes; (void)n_in; (void)out_size; (void)ws_size;
  const float* inputs  = (const float*)d_in[0];
  const int*   parents = (const int*)d_in[1];
  const float* Wiou    = (const float*)d_in[2];
  const float* biou    = (const float*)d_in[3];
  const float* Uiou    = (const float*)d_in[4];
  const float* Wf      = (const float*)d_in[5];
  const float* bf_     = (const float*)d_in[6];
  const float* Uf      = (const float*)d_in[7];
  float* out = (float*)d_out;
  char* ws = (char*)d_ws;

  float* fcsum = (float*)(ws + OFF_FCSUM);
  unsigned* hx = (unsigned*)(ws + OFF_HX);
  float* gsum  = (float*)(ws + OFF_GSUM);
  float* xf    = (float*)(ws + OFF_XF);
  unsigned short* bth = (unsigned short*)(ws + OFF_BTH);
  unsigned short* btl = (unsigned short*)(ws + OFF_BTL);
  unsigned short* uh  = (unsigned short*)(ws + OFF_UH);
  unsigned short* ul  = (unsigned short*)(ws + OFF_UL);
  unsigned short* ath = (unsigned short*)(ws + OFF_ATH);  // aliases fcsum+hx (pre-gemm only)
  unsigned short* atl = (unsigned short*)(ws + OFF_ATL);

  hipFuncSetAttribute((const void*)gemm_split_kernel,
                      hipFuncAttributeMaxDynamicSharedMemorySize, 65536);

  // Phase 1: precompute bf16 splits (A buffers live in the fcsum+hx alias region)
  cvt_w_kernel<<<2048, 256, 0, stream>>>(Wiou, Wf, bth, btl);
  cvt_u_kernel<<<1024, 256, 0, stream>>>(Uiou, Uf, uh, ul);
  cvt_a_kernel<<<32768, 256, 0, stream>>>(inputs, ath, atl);
  // Phase 2: input GEMM (3-term, fp32-accurate)
  gemm_split_kernel<<<4096, 256, 65536, stream>>>(ath, atl, bth, btl, biou, bf_, gsum, xf);
  // Phase 3: scan-state init (overwrites the alias region AFTER gemm is done)
  hipMemsetAsync(ws + OFF_FCSUM, 0, SZ_FCSUM, stream);    // fcsum zeros
  hipMemsetAsync(ws + OFF_HX, 0xFF, SZ_HX, stream);       // hx poison (invalid exponent)
  // Phase 4: sequential scan (2-term recurrence)
  scan_kernel<<<64, 512, 0, stream>>>(uh, ul, xf, parents, gsum, fcsum, hx, out);
}